// Round 10
// baseline (235.586 us; speedup 1.0000x reference)
//
#include <hip/hip_runtime.h>
#include <hip/hip_fp16.h>

// Problem constants (fixed by reference setup_inputs)
#define N_NODES 50000
#define E_RAND  1600000
#define IN_F    8
#define OUT_F   8
#define BATCH   16
#define T_TYPES 5

#define NSUP    196      // supers of 256 dst nodes (dst>>8)
#define NHB     1563     // half-buckets of 32 dst nodes (dst>>5)
#define NKEY    (NSUP * 1024)   // 200704 key slots; global key = hb*128 + local

#define CHUNK      6144
#define CNT_BLOCKS ((E_RAND + CHUNK - 1) / CHUNK)   // 261
#define CONV_BLOCKS 1563                            // ceil(N/32)

#define SCAP 8832        // per-super capacity: mean 8192 + ~7 sigma
#define LCAP 1408        // per-hb capacity: mean 1024 + ~12 sigma (R2-proven)

// Workspace layout (bytes). Total 20,248,576 (< proven-available 20,411,392).
//   B1  : (NSUP+1) ints — exact super base offsets (+ sentinel E_RAND)
//   T   : NSUP ints     — super totals (scan intermediate)
//   H   : [261][196] u16 — per-(block,super) counts -> scanned bases in place
//   seg : NKEY ints     — ABSOLUTE segment offsets per global key (node,type)
//   xh  : N*128 fp16    — x transposed to [n][b][i] (12.8 MB)
//   bin : E_RAND ints   — payload (key<<16)|src, key=(dst&255)*4+(et-2);
//                         super-ordered by scatter, then key-sorted IN PLACE
#define OFF_B1   0
#define OFF_T    1024
#define OFF_H    2048
#define OFF_SEG  106496
#define OFF_XH   1048576
#define OFF_BIN  13848576
#define WS_NEEDED 20248576

// ---------------------------------------------------------------------------
// K1: super-count || convert fused (split grid).
//   blocks [0,261): LDS hist of a 6144-edge chunk over 196 supers -> H row
//     (coalesced u16, zero global atomics).
//   blocks [261, +1563): x [n][i][b] fp32 -> xh [n][b][i] fp16 (proven body).
// ---------------------------------------------------------------------------
__global__ __launch_bounds__(512)
void count_conv_kernel(const float* __restrict__ x, __half* __restrict__ xh,
                       const int* __restrict__ dst, unsigned short* __restrict__ H) {
    if (blockIdx.x < CNT_BLOCKS) {
        __shared__ int h[NSUP];
        const int t = threadIdx.x;
        if (t < NSUP) h[t] = 0;
        __syncthreads();
        const int cbase = blockIdx.x * CHUNK;
#pragma unroll 4
        for (int k = 0; k < CHUNK / 512; ++k) {
            const int e = cbase + k * 512 + t;
            if (e < E_RAND) atomicAdd(&h[dst[N_NODES + e] >> 8], 1);
        }
        __syncthreads();
        if (t < NSUP) H[(size_t)blockIdx.x * NSUP + t] = (unsigned short)h[t];
        return;
    }
    const int b = threadIdx.x & 15;
    const int n = (blockIdx.x - CNT_BLOCKS) * 32 + (threadIdx.x >> 4);
    if (n >= N_NODES) return;
    const float* xp = x + n * (IN_F * BATCH) + b;
    union { __half hh[8]; uint4 u; } pk;
#pragma unroll
    for (int i = 0; i < IN_F; ++i) pk.hh[i] = __float2half(xp[i * BATCH]);
    *(uint4*)(xh + (size_t)n * 128 + b * 8) = pk.u;
}

// ---------------------------------------------------------------------------
// K2: per-super-column exclusive scan over the 261 block rows (in place) +
// column totals -> T. 16 cols/block, LDS tile padded [261][17]. (R9-proven.)
// ---------------------------------------------------------------------------
__global__ __launch_bounds__(256)
void scan_kernel(unsigned short* __restrict__ H, int* __restrict__ T) {
    __shared__ int Hl[CNT_BLOCKS][17];
    const int t  = threadIdx.x;
    const int c0 = blockIdx.x * 16;
    for (int idx = t; idx < CNT_BLOCKS * 16; idx += 256) {
        const int blk = idx >> 4, j = idx & 15, su = c0 + j;
        Hl[blk][j] = (su < NSUP) ? (int)H[(size_t)blk * NSUP + su] : 0;
    }
    __syncthreads();
    const int lane = t & 63;
    const int w    = t >> 6;
#pragma unroll
    for (int jj = 0; jj < 4; ++jj) {
        const int j = w * 4 + jj;
        int carry = 0;
#pragma unroll
        for (int c = 0; c < 5; ++c) {                // ceil(261/64)=5
            const int blk = c * 64 + lane;
            const int v = (blk < CNT_BLOCKS) ? Hl[blk][j] : 0;
            int inc = v;
#pragma unroll
            for (int d = 1; d < 64; d <<= 1) {
                const int u = __shfl_up(inc, d);
                if (lane >= d) inc += u;
            }
            if (blk < CNT_BLOCKS) Hl[blk][j] = carry + inc - v;
            carry += __shfl(inc, 63);
        }
        if (lane == 0 && c0 + j < NSUP) T[c0 + j] = carry;
    }
    __syncthreads();
    for (int idx = t; idx < CNT_BLOCKS * 16; idx += 256) {
        const int blk = idx >> 4, j = idx & 15, su = c0 + j;
        if (su < NSUP) H[(size_t)blk * NSUP + su] = (unsigned short)Hl[blk][j];
    }
}

// ---------------------------------------------------------------------------
// K3: exclusive scan of T[196] -> B1 (+ sentinel). One wave, 4 chunks.
// ---------------------------------------------------------------------------
__global__ __launch_bounds__(64)
void scan2_kernel(const int* __restrict__ T, int* __restrict__ B1) {
    const int lane = threadIdx.x;
    int carry = 0;
    for (int c = 0; c * 64 < NSUP; ++c) {
        const int idx = c * 64 + lane;
        const int v = (idx < NSUP) ? T[idx] : 0;
        int inc = v;
#pragma unroll
        for (int d = 1; d < 64; d <<= 1) {
            const int u = __shfl_up(inc, d);
            if (lane >= d) inc += u;
        }
        if (idx < NSUP) B1[idx] = carry + inc - v;
        carry += __shfl(inc, 63);
    }
    if (lane == 0) B1[NSUP] = E_RAND;
}

// ---------------------------------------------------------------------------
// K4: scatter edges into exact super-ordered positions. Runs avg 31 edges
// (124 B) -> write amp ~1.2x (vs 4x at hb granularity — R9's 55us pig).
// payload = ((dst&255)*4 + (et-2))<<16 | src. Zero global atomics.
// ---------------------------------------------------------------------------
__global__ __launch_bounds__(512)
void scatter_kernel(const int* __restrict__ src, const int* __restrict__ dst,
                    const int* __restrict__ et,
                    const unsigned short* __restrict__ H,
                    const int* __restrict__ B1,
                    int* __restrict__ binned) {
    __shared__ int h[NSUP];
    __shared__ int lbase[NSUP];
    const int t = threadIdx.x;
    if (t < NSUP) {
        h[t] = 0;
        lbase[t] = B1[t] + (int)H[(size_t)blockIdx.x * NSUP + t];
    }
    __syncthreads();
    const int cbase = blockIdx.x * CHUNK;
#pragma unroll 4
    for (int k = 0; k < CHUNK / 512; ++k) {
        const int e = cbase + k * 512 + t;
        if (e < E_RAND) {
            const int ee = N_NODES + e;
            const int d  = dst[ee];
            const int su = d >> 8;
            const int payload = ((((d & 255) << 2) | (et[ee] - 2)) << 16) | src[ee];
            binned[lbase[su] + atomicAdd(&h[su], 1)] = payload;
        }
    }
}

// ---------------------------------------------------------------------------
// K5: per-super key sort IN PLACE (196 blocks x 512). Stages the exact run
// in LDS (race-free in-place overwrite), 1024-key counting sort, writes
// sorted payloads back + ABSOLUTE segoff[su*1024 + k] (coalesced). After
// this, gather needs NO sort: segments are contiguous, ordered by
// (node,type) within super == global (node,type) order.
// ---------------------------------------------------------------------------
__global__ __launch_bounds__(512)
void sort_kernel(const int* __restrict__ B1, int* __restrict__ binned,
                 int* __restrict__ segoff) {
    __shared__ int pay[SCAP];
    __shared__ int hist[1024];
    __shared__ int cur[1024];
    const int su  = blockIdx.x;
    const int s0  = B1[su];
    const int cnt = B1[su + 1] - s0;
    const int t   = threadIdx.x;

    for (int k = t; k < 1024; k += 512) hist[k] = 0;
    __syncthreads();
    for (int i = t; i < cnt; i += 512) {
        const int p = binned[s0 + i];
        pay[i] = p;
        atomicAdd(&hist[p >> 16], 1);
    }
    __syncthreads();
    if (t < 64) {                        // single-wave serial-carry scan, 16 chunks
        int carry = 0;
#pragma unroll
        for (int c = 0; c < 16; ++c) {
            const int k = c * 64 + t;
            const int v = hist[k];
            int inc = v;
#pragma unroll
            for (int d = 1; d < 64; d <<= 1) {
                const int u = __shfl_up(inc, d);
                if (t >= d) inc += u;
            }
            cur[k] = carry + inc - v;
            carry += __shfl(inc, 63);
        }
    }
    __syncthreads();
    for (int k = t; k < 1024; k += 512) segoff[su * 1024 + k] = s0 + cur[k];
    __syncthreads();                     // segoff reads of cur done before mutation
    for (int i = t; i < cnt; i += 512) {
        const int p = pay[i];
        binned[s0 + atomicAdd(&cur[p >> 16], 1)] = p;
    }
}

// ---------------------------------------------------------------------------
// K6: XCD-quarter-aligned gather (ONE dispatch, 6256 blocks x 256).
//   block -> (hb, q): xcd = bid&7 (HW round-robin), q = xcd&3,
//   hb = (bid>>3)*2 + (xcd>>2). Each XCD processes ONE batch quarter ->
//   its xh working set = 3.2 MB quarter-lines, resident in its 4 MB L2.
//   (R8's quartering failed because phases interleaved TEMPORALLY; this
//   aligns them SPATIALLY — one dispatch, no fragility.)
//   Group of 16 lanes per node: 4 edge slots (es) x 4 batch cols (bq);
//   4 bq lanes read one edge's contiguous 64B quarter-row; butterfly
//   shfl_xor(4,8) sums edge slots; lane computes outputs o=2es,2es+1.
// ---------------------------------------------------------------------------
__device__ __forceinline__ void unpack_add(uint4 v, float* xa) {
    const __half2* hp = (const __half2*)&v;
    float2 f;
    f = __half22float2(hp[0]); xa[0] += f.x; xa[1] += f.y;
    f = __half22float2(hp[1]); xa[2] += f.x; xa[3] += f.y;
    f = __half22float2(hp[2]); xa[4] += f.x; xa[5] += f.y;
    f = __half22float2(hp[3]); xa[6] += f.x; xa[7] += f.y;
}

__global__ __launch_bounds__(256)
void gather_kernel(const __half* __restrict__ xh,
                   const float* __restrict__ W,
                   const float* __restrict__ Bv,
                   const int* __restrict__ segoff,
                   const int* __restrict__ binned,
                   float* __restrict__ y) {
    __shared__ unsigned short lsu[LCAP];
    __shared__ int   sg[129];
    __shared__ float Wl[T_TYPES * OUT_F * IN_F];   // 320
    __shared__ float Bvl[T_TYPES * OUT_F];         // 40

    const int bid = blockIdx.x;
    const int xcd = bid & 7;
    const int q   = xcd & 3;
    const int hb  = (bid >> 3) * 2 + (xcd >> 2);
    if (hb >= NHB) return;                         // block-uniform: safe

    const int t = threadIdx.x;
    for (int i = t; i < 320; i += 256) Wl[i] = W[i];
    if (t >= 192 && t < 232) Bvl[t - 192] = Bv[t - 192];
    if (t < 129) sg[t] = segoff[hb * 128 + t];
    __syncthreads();

    const int s0g = sg[0];
    const int cnt = sg[128] - s0g;
    for (int i = t; i < cnt; i += 256)
        lsu[i] = (unsigned short)(__builtin_nontemporal_load(&binned[s0g + i]) & 0xFFFF);
    __syncthreads();

    const int g  = t >> 4;           // group 0..15
    const int l  = t & 15;
    const int es = l >> 2;           // edge slot 0..3
    const int bq = l & 3;            // batch col within quarter
    const int b  = q * 4 + bq;
    const int o0 = es * 2;           // this lane's output rows
    const __half* __restrict__ xb = xh + b * 8;

#pragma unroll
    for (int half = 0; half < 2; ++half) {
        const int ln = g + half * 16;               // local node 0..31
        const int n  = hb * 32 + ln;
        if (n >= N_NODES) continue;

        // self loop (W[0], Bv[0])
        float xa[IN_F];
#pragma unroll
        for (int i = 0; i < IN_F; ++i) xa[i] = 0.f;
        unpack_add(*(const uint4*)(xb + (size_t)n * 128), xa);

        float out0 = Bvl[o0];
        float out1 = Bvl[o0 + 1];
#pragma unroll
        for (int i = 0; i < IN_F; ++i) {
            out0 = fmaf(Wl[o0 * IN_F + i],       xa[i], out0);
            out1 = fmaf(Wl[(o0 + 1) * IN_F + i], xa[i], out1);
        }

        const int* sp = sg + ln * 4;
#pragma unroll
        for (int t4 = 0; t4 < 4; ++t4) {
            const int s0 = sp[t4] - s0g;
            const int s1 = sp[t4 + 1] - s0g;
            const int c  = s1 - s0;
            if (c == 0) continue;

#pragma unroll
            for (int i = 0; i < IN_F; ++i) xa[i] = 0.f;

            for (int e = s0 + es; e < s1; e += 4) {
                const int srcn = lsu[e];
                unpack_add(*(const uint4*)(xb + (size_t)srcn * 128), xa);
            }
            // sum the 4 edge slots (lane bits 2-3; bq bits untouched)
#pragma unroll
            for (int i = 0; i < IN_F; ++i) {
                xa[i] += __shfl_xor(xa[i], 4);
                xa[i] += __shfl_xor(xa[i], 8);
            }

            const float* Wt = Wl + (t4 + 1) * (OUT_F * IN_F);
            const float* Bt = Bvl + (t4 + 1) * OUT_F;
            const float fc = (float)c;
            out0 = fmaf(fc, Bt[o0],     out0);
            out1 = fmaf(fc, Bt[o0 + 1], out1);
#pragma unroll
            for (int i = 0; i < IN_F; ++i) {
                out0 = fmaf(Wt[o0 * IN_F + i],       xa[i], out0);
                out1 = fmaf(Wt[(o0 + 1) * IN_F + i], xa[i], out1);
            }
        }

        float* yp = y + (size_t)n * (OUT_F * BATCH);
        __builtin_nontemporal_store(out0, &yp[o0 * BATCH + b]);
        __builtin_nontemporal_store(out1, &yp[(o0 + 1) * BATCH + b]);
    }
}

// ---------------------------------------------------------------------------
// Fallback tier (ws too small): self-loop y init + per-edge matmul w/ atomics
// ---------------------------------------------------------------------------
__global__ __launch_bounds__(256)
void selfinit_kernel(const float* __restrict__ x,
                     const float* __restrict__ W,
                     const float* __restrict__ Bv,
                     float* __restrict__ y) {
    const int b = threadIdx.x & (BATCH - 1);
    const int n = blockIdx.x * 16 + (threadIdx.x >> 4);
    if (n >= N_NODES) return;
    float xc[IN_F];
#pragma unroll
    for (int i = 0; i < IN_F; ++i) xc[i] = x[(n * IN_F + i) * BATCH + b];
#pragma unroll
    for (int o = 0; o < OUT_F; ++o) {
        float a = Bv[o];
#pragma unroll
        for (int i = 0; i < IN_F; ++i) a = fmaf(W[o * IN_F + i], xc[i], a);
        y[(n * OUT_F + o) * BATCH + b] = a;
    }
}

__global__ __launch_bounds__(256)
void direct_edge_kernel(const float* __restrict__ x,
                        const float* __restrict__ W,
                        const float* __restrict__ Bv,
                        const int* __restrict__ src,
                        const int* __restrict__ dst,
                        const int* __restrict__ et,
                        float* __restrict__ y) {
    const int tid = blockIdx.x * 256 + threadIdx.x;
    const int eg  = tid >> 4;
    const int b   = tid & (BATCH - 1);
    if (eg >= E_RAND) return;
    const int e  = N_NODES + eg;
    const int s  = src[e];
    const int d  = dst[e];
    const int ti = et[e] - 1;
    const float* __restrict__ Wt = W + ti * (OUT_F * IN_F);
    float xc[IN_F];
#pragma unroll
    for (int i = 0; i < IN_F; ++i) xc[i] = x[(s * IN_F + i) * BATCH + b];
    float* yp = y + (size_t)d * (OUT_F * BATCH) + b;
#pragma unroll
    for (int o = 0; o < OUT_F; ++o) {
        float a = Bv[ti * OUT_F + o];
#pragma unroll
        for (int i = 0; i < IN_F; ++i) a = fmaf(Wt[o * IN_F + i], xc[i], a);
        unsafeAtomicAdd(yp + o * BATCH, a);
    }
}

extern "C" void kernel_launch(void* const* d_in, const int* in_sizes, int n_in,
                              void* d_out, int out_size, void* d_ws, size_t ws_size,
                              hipStream_t stream) {
    const float* x   = (const float*)d_in[0];
    const float* W   = (const float*)d_in[1];
    const float* Bv  = (const float*)d_in[2];
    const int*   src = (const int*)d_in[3];
    const int*   dst = (const int*)d_in[4];
    const int*   et  = (const int*)d_in[5];
    float* y = (float*)d_out;

    char* ws = (char*)d_ws;
    int*            B1     = (int*)(ws + OFF_B1);
    int*            T      = (int*)(ws + OFF_T);
    unsigned short* H      = (unsigned short*)(ws + OFF_H);
    int*            segoff = (int*)(ws + OFF_SEG);
    __half*         xh     = (__half*)(ws + OFF_XH);
    int*            binned = (int*)(ws + OFF_BIN);

    if (ws_size >= WS_NEEDED) {
        count_conv_kernel<<<CNT_BLOCKS + CONV_BLOCKS, 512, 0, stream>>>(x, xh, dst, H);
        scan_kernel<<<(NSUP + 15) / 16, 256, 0, stream>>>(H, T);
        scan2_kernel<<<1, 64, 0, stream>>>(T, B1);
        scatter_kernel<<<CNT_BLOCKS, 512, 0, stream>>>(src, dst, et, H, B1, binned);
        sort_kernel<<<NSUP, 512, 0, stream>>>(B1, binned, segoff);
        gather_kernel<<<782 * 8, 256, 0, stream>>>(xh, W, Bv, segoff, binned, y);
    } else {
        selfinit_kernel<<<(N_NODES + 15) / 16, 256, 0, stream>>>(x, W, Bv, y);
        direct_edge_kernel<<<(E_RAND * 16 + 255) / 256, 256, 0, stream>>>(x, W, Bv, src, dst, et, y);
    }
}